// Round 6
// baseline (104.348 us; speedup 1.0000x reference)
//
#include <hip/hip_runtime.h>
#include <hip/hip_bf16.h>

typedef unsigned short u16;
typedef unsigned int u32;
typedef unsigned long long u64;
typedef short s8v __attribute__((ext_vector_type(8)));
typedef float f4v __attribute__((ext_vector_type(4)));

#define DMODEL 2048

__device__ __forceinline__ u16 f2bf(float f) {
  unsigned u = __float_as_uint(f);
  u += 0x7fffu + ((u >> 16) & 1u);
  return (u16)(u >> 16);
}

__device__ __forceinline__ u32 pkbf(float lo, float hi) {
  __hip_bfloat162 h = __float22bfloat162_rn(make_float2(lo, hi));
  return *reinterpret_cast<const u32*>(&h);
}

// ---------------- kernel 1: Wcb[32][2048] bf16 + bias2 + zero scan flags ----------------
__global__ __launch_bounds__(256) void build_wc(const float* __restrict__ dtw,
                                                const float* __restrict__ dtpw,
                                                const float* __restrict__ dtb,
                                                const float* __restrict__ Bm,
                                                u16* __restrict__ Wcb,
                                                float* __restrict__ bias2,
                                                u32* __restrict__ status) {
  __shared__ float spw[512 * 16];
  __shared__ float sdw[64][16];
  const int t = threadIdx.x;
  const int k0 = blockIdx.x * 16;
  if (blockIdx.x < 2) status[blockIdx.x * 256 + t] = 0u;   // 512 flags
  for (int i = t; i < 2048; i += 256)
    *(float4*)&spw[i * 4] = *(const float4*)&dtpw[i * 4];
  const int kk = t >> 4, n = t & 15;
  const int srr = t >> 2, sc4 = (t & 3) * 4;
  float acc = 0.f;
  for (int rc = 0; rc < 8; ++rc) {
    __syncthreads();
    *(float4*)&sdw[srr][sc4] = *(const float4*)&dtw[(rc * 64 + srr) * DMODEL + k0 + sc4];
    __syncthreads();
#pragma unroll 8
    for (int rr = 0; rr < 64; ++rr)
      acc += sdw[rr][kk] * spw[(rc * 64 + rr) * 16 + n];
  }
  Wcb[n * DMODEL + k0 + kk] = f2bf(acc);
  Wcb[(16 + n) * DMODEL + k0 + kk] = f2bf(Bm[(k0 + kk) * 16 + n]);
  if (blockIdx.x == 0 && t < 16) {
    float s0 = 0.f, s1 = 0.f;
    for (int r = 0; r < 512; r += 2) {
      s0 += dtb[r] * spw[r * 16 + t];
      s1 += dtb[r + 1] * spw[(r + 1) * 16 + t];
    }
    bias2[t] = s0 + s1;
  }
}

// ---------------- kernel 2: mega — GEMM + chunked scan + projection ----------------
// 512 blocks x 512 thr. Block bid: b = bid>>7, chunk c = bid&127, rows [bid*16, bid*16+16).
__global__ __launch_bounds__(512) void mega(const float* __restrict__ x,
                                            const u16* __restrict__ Wcb,
                                            const float* __restrict__ bias2,
                                            const float* __restrict__ Alog,
                                            const float* __restrict__ C,
                                            u64* __restrict__ agg,
                                            u32* __restrict__ status,
                                            float* __restrict__ y) {
  __shared__ float red[8][8][64];            // 16 KB
  __shared__ float aL[16][17], xL[16][17];   // 2.2 KB
  __shared__ float sAX[128][16][2];          // 16 KB
  __shared__ float sh[16][16];               // 1 KB
  const int t = threadIdx.x, w = t >> 6, l = t & 63;
  const int lr = l & 15, lh = l >> 4;
  const int bid = blockIdx.x;
  const int b = bid >> 7, c = bid & 127;
  const long row0 = (long)bid * 16;

  // ---- phase A: GEMM (x -> delta2 | xB for 16 rows) ----
  f4v acc0 = {0.f, 0.f, 0.f, 0.f}, acc1 = {0.f, 0.f, 0.f, 0.f};
  const int k0 = w * 256;
  const float* xp  = x + (row0 + lr) * DMODEL + k0 + lh * 8;
  const u16*   wp0 = Wcb + lr * DMODEL + k0 + lh * 8;
  const u16*   wp1 = Wcb + (16 + lr) * DMODEL + k0 + lh * 8;
#pragma unroll
  for (int ks = 0; ks < 8; ++ks) {
    f4v u0 = __builtin_nontemporal_load((const f4v*)(xp + ks * 32));
    f4v u1 = __builtin_nontemporal_load((const f4v*)(xp + ks * 32 + 4));
    union { u32 d[4]; s8v v; } pa;
    pa.d[0] = pkbf(u0[0], u0[1]); pa.d[1] = pkbf(u0[2], u0[3]);
    pa.d[2] = pkbf(u1[0], u1[1]); pa.d[3] = pkbf(u1[2], u1[3]);
    s8v b0 = *(const s8v*)(wp0 + ks * 32);
    s8v b1 = *(const s8v*)(wp1 + ks * 32);
    acc0 = __builtin_amdgcn_mfma_f32_16x16x32_bf16(pa.v, b0, acc0, 0, 0, 0);
    acc1 = __builtin_amdgcn_mfma_f32_16x16x32_bf16(pa.v, b1, acc1, 0, 0, 0);
  }
#pragma unroll
  for (int q = 0; q < 4; ++q) { red[q][w][l] = acc0[q]; red[4 + q][w][l] = acc1[q]; }
  __syncthreads();
  {
    float s = 0.f;
#pragma unroll
    for (int ww = 0; ww < 8; ++ww) s += red[w][ww][l];
    const int n = lr;
    const int row = lh * 4 + (w & 3);
    if (w < 4) {
      float d2 = s + bias2[n];
      float sig = 1.f / (1.f + __expf(-d2));
      float delta = 0.001f + 0.099f * sig;
      aL[row][n] = __expf(delta * __expf(Alog[n]));
    } else {
      xL[row][n] = s;
    }
  }
  __syncthreads();

  // ---- phase B: publish chunk aggregate (A,X) per n ----
  if (t < 16) {
    float A = 1.f, X = 0.f;
#pragma unroll
    for (int r = 0; r < 16; ++r) {
      float a = aL[r][t];
      X = a * X + xL[r][t];
      A *= a;
    }
    u64 v = (u64)__float_as_uint(A) | ((u64)__float_as_uint(X) << 32);
    __hip_atomic_store(&agg[(u64)bid * 16 + t], v, __ATOMIC_RELAXED, __HIP_MEMORY_SCOPE_AGENT);
  }
  __syncthreads();   // drains the agg stores of t<16
  if (t == 0)
    __hip_atomic_store(&status[bid], 1u, __ATOMIC_RELEASE, __HIP_MEMORY_SCOPE_AGENT);

  // ---- phase C: gather predecessor aggregates, tree-compose in order ----
  {
    const int j = t >> 2, n0 = (t & 3) * 4;
    if (j < c) {
      while (__hip_atomic_load(&status[b * 128 + j], __ATOMIC_ACQUIRE,
                               __HIP_MEMORY_SCOPE_AGENT) == 0u)
        __builtin_amdgcn_s_sleep(1);
#pragma unroll
      for (int q = 0; q < 4; ++q) {
        u64 v = __hip_atomic_load(&agg[((u64)b * 128 + j) * 16 + n0 + q],
                                  __ATOMIC_RELAXED, __HIP_MEMORY_SCOPE_AGENT);
        sAX[j][n0 + q][0] = __uint_as_float((u32)v);
        sAX[j][n0 + q][1] = __uint_as_float((u32)(v >> 32));
      }
    } else {
#pragma unroll
      for (int q = 0; q < 4; ++q) { sAX[j][n0 + q][0] = 1.f; sAX[j][n0 + q][1] = 0.f; }
    }
  }
  __syncthreads();
  for (int st = 1; st < 128; st <<= 1) {
    const int cnt = (128 / (2 * st)) * 16;
    for (int idx = t; idx < cnt; idx += 512) {
      const int jj = (idx >> 4) * 2 * st, n = idx & 15;
      float A1 = sAX[jj][n][0], X1 = sAX[jj][n][1];
      float A2 = sAX[jj + st][n][0], X2 = sAX[jj + st][n][1];
      sAX[jj][n][0] = A2 * A1;          // apply [jj] then [jj+st]
      sAX[jj][n][1] = A2 * X1 + X2;
    }
    __syncthreads();
  }

  // ---- phase D: reconstruct h for the 16 rows ----
  if (t < 16) {
    float h = sAX[0][t][1];             // state entering this chunk (h0 = 0)
#pragma unroll
    for (int r = 0; r < 16; ++r) {
      h = aL[r][t] * h + xL[r][t];
      sh[r][t] = h;
    }
  }
  __syncthreads();

  // ---- phase E: y[16 rows] = h . C ----
  f4v c16[16];
#pragma unroll
  for (int nn = 0; nn < 16; ++nn)
    c16[nn] = *(const f4v*)&C[nn * DMODEL + t * 4];
#pragma unroll 2
  for (int r = 0; r < 16; ++r) {
    f4v o = {0.f, 0.f, 0.f, 0.f};
#pragma unroll
    for (int nn = 0; nn < 16; ++nn) o += sh[r][nn] * c16[nn];
    __builtin_nontemporal_store(o, (f4v*)&y[(row0 + r) * DMODEL + t * 4]);
  }
}

extern "C" void kernel_launch(void* const* d_in, const int* in_sizes, int n_in,
                              void* d_out, int out_size, void* d_ws, size_t ws_size,
                              hipStream_t stream) {
  const float* x    = (const float*)d_in[0];
  const float* Alog = (const float*)d_in[1];
  const float* Bm   = (const float*)d_in[2];
  const float* Cm   = (const float*)d_in[3];
  const float* dtw  = (const float*)d_in[4];
  const float* dtb  = (const float*)d_in[5];
  const float* dtpw = (const float*)d_in[6];
  float* y = (float*)d_out;

  char* w = (char*)d_ws;
  u16*   Wcb   = (u16*)w; w += (size_t)32 * DMODEL * 2;   // 128 KB
  float* bias2 = (float*)w; w += 256;
  u64*   agg   = (u64*)w; w += (size_t)512 * 16 * 8;      // 64 KB
  u32*   stat  = (u32*)w; w += (size_t)512 * 4;           // 2 KB

  build_wc<<<128, 256, 0, stream>>>(dtw, dtpw, dtb, Bm, Wcb, bias2, stat);
  mega<<<512, 512, 0, stream>>>(x, Wcb, bias2, Alog, Cm, agg, stat, y);
}

// Round 7
// 98.829 us; speedup vs baseline: 1.0558x; 1.0558x over previous
//
#include <hip/hip_runtime.h>
#include <hip/hip_bf16.h>

typedef unsigned short u16;
typedef unsigned int u32;
typedef unsigned long long u64;
typedef short s8v __attribute__((ext_vector_type(8)));
typedef float f4v __attribute__((ext_vector_type(4)));

#define DMODEL 2048

__device__ __forceinline__ u16 f2bf(float f) {
  unsigned u = __float_as_uint(f);
  u += 0x7fffu + ((u >> 16) & 1u);
  return (u16)(u >> 16);
}

__device__ __forceinline__ u32 pkbf(float lo, float hi) {
  __hip_bfloat162 h = __float22bfloat162_rn(make_float2(lo, hi));
  return *reinterpret_cast<const u32*>(&h);
}

// ---------------- kernel 1: Wcb[32][2048] bf16 + bias2 + zero scan flags ----------------
__global__ __launch_bounds__(256) void build_wc(const float* __restrict__ dtw,
                                                const float* __restrict__ dtpw,
                                                const float* __restrict__ dtb,
                                                const float* __restrict__ Bm,
                                                u16* __restrict__ Wcb,
                                                float* __restrict__ bias2,
                                                u32* __restrict__ status) {
  __shared__ float spw[512 * 16];
  __shared__ float sdw[64][16];
  const int t = threadIdx.x;
  const int k0 = blockIdx.x * 16;
  if (blockIdx.x < 2) status[blockIdx.x * 256 + t] = 0u;   // 512 flags
  for (int i = t; i < 2048; i += 256)
    *(float4*)&spw[i * 4] = *(const float4*)&dtpw[i * 4];
  const int kk = t >> 4, n = t & 15;
  const int srr = t >> 2, sc4 = (t & 3) * 4;
  float acc = 0.f;
  for (int rc = 0; rc < 8; ++rc) {
    __syncthreads();
    *(float4*)&sdw[srr][sc4] = *(const float4*)&dtw[(rc * 64 + srr) * DMODEL + k0 + sc4];
    __syncthreads();
#pragma unroll 8
    for (int rr = 0; rr < 64; ++rr)
      acc += sdw[rr][kk] * spw[(rc * 64 + rr) * 16 + n];
  }
  Wcb[n * DMODEL + k0 + kk] = f2bf(acc);
  Wcb[(16 + n) * DMODEL + k0 + kk] = f2bf(Bm[(k0 + kk) * 16 + n]);
  if (blockIdx.x == 0 && t < 16) {
    float s0 = 0.f, s1 = 0.f;
    for (int r = 0; r < 512; r += 2) {
      s0 += dtb[r] * spw[r * 16 + t];
      s1 += dtb[r + 1] * spw[(r + 1) * 16 + t];
    }
    bias2[t] = s0 + s1;
  }
}

// ---------------- kernel 2: mega — GEMM + chunked scan + projection ----------------
// 512 blocks x 512 thr. Block bid: b = bid>>7, chunk c = bid&127, rows [bid*16, bid*16+16).
__global__ __launch_bounds__(512) void mega(const float* __restrict__ x,
                                            const u16* __restrict__ Wcb,
                                            const float* __restrict__ bias2,
                                            const float* __restrict__ Alog,
                                            const float* __restrict__ C,
                                            u64* __restrict__ agg,
                                            u32* __restrict__ status,
                                            float* __restrict__ y) {
  __shared__ float red[8][8][64];            // 16 KB
  __shared__ float aL[16][17], xL[16][17];   // 2.2 KB
  __shared__ float sAX[128][16][2];          // 16 KB
  __shared__ float sh[16][16];               // 1 KB
  const int t = threadIdx.x, w = t >> 6, l = t & 63;
  const int lr = l & 15, lh = l >> 4;
  const int bid = blockIdx.x;
  const int b = bid >> 7, c = bid & 127;
  const long row0 = (long)bid * 16;

  // ---- phase A: GEMM (x -> delta2 | xB for 16 rows) ----
  f4v acc0 = {0.f, 0.f, 0.f, 0.f}, acc1 = {0.f, 0.f, 0.f, 0.f};
  const int k0 = w * 256;
  const float* xp  = x + (row0 + lr) * DMODEL + k0 + lh * 8;
  const u16*   wp0 = Wcb + lr * DMODEL + k0 + lh * 8;
  const u16*   wp1 = Wcb + (16 + lr) * DMODEL + k0 + lh * 8;
#pragma unroll
  for (int ks = 0; ks < 8; ++ks) {
    f4v u0 = __builtin_nontemporal_load((const f4v*)(xp + ks * 32));
    f4v u1 = __builtin_nontemporal_load((const f4v*)(xp + ks * 32 + 4));
    union { u32 d[4]; s8v v; } pa;
    pa.d[0] = pkbf(u0[0], u0[1]); pa.d[1] = pkbf(u0[2], u0[3]);
    pa.d[2] = pkbf(u1[0], u1[1]); pa.d[3] = pkbf(u1[2], u1[3]);
    s8v b0 = *(const s8v*)(wp0 + ks * 32);
    s8v b1 = *(const s8v*)(wp1 + ks * 32);
    acc0 = __builtin_amdgcn_mfma_f32_16x16x32_bf16(pa.v, b0, acc0, 0, 0, 0);
    acc1 = __builtin_amdgcn_mfma_f32_16x16x32_bf16(pa.v, b1, acc1, 0, 0, 0);
  }
#pragma unroll
  for (int q = 0; q < 4; ++q) { red[q][w][l] = acc0[q]; red[4 + q][w][l] = acc1[q]; }
  __syncthreads();
  {
    float s = 0.f;
#pragma unroll
    for (int ww = 0; ww < 8; ++ww) s += red[w][ww][l];
    const int n = lr;
    const int row = lh * 4 + (w & 3);
    if (w < 4) {
      float d2 = s + bias2[n];
      float sig = 1.f / (1.f + __expf(-d2));
      float delta = 0.001f + 0.099f * sig;
      aL[row][n] = __expf(delta * __expf(Alog[n]));
    } else {
      xL[row][n] = s;
    }
  }
  __syncthreads();

  // ---- phase B: publish chunk aggregate (A,X) per n ----
  if (t < 16) {
    float A = 1.f, X = 0.f;
#pragma unroll
    for (int r = 0; r < 16; ++r) {
      float a = aL[r][t];
      X = a * X + xL[r][t];
      A *= a;
    }
    u64 v = (u64)__float_as_uint(A) | ((u64)__float_as_uint(X) << 32);
    __hip_atomic_store(&agg[(u64)bid * 16 + t], v, __ATOMIC_RELAXED, __HIP_MEMORY_SCOPE_AGENT);
  }
  __syncthreads();   // drains vmcnt: agg stores globally visible before flag
  if (t == 0)
    __hip_atomic_store(&status[bid], 1u, __ATOMIC_RELEASE, __HIP_MEMORY_SCOPE_AGENT);

  // ---- phase C: wait for predecessors (RELAXED polls, 1 thread per flag) ----
  if (t < c) {
    while (__hip_atomic_load(&status[b * 128 + t], __ATOMIC_RELAXED,
                             __HIP_MEMORY_SCOPE_AGENT) == 0u)
      __builtin_amdgcn_s_sleep(4);
  }
  __syncthreads();
  __builtin_amdgcn_fence(__ATOMIC_ACQUIRE, "agent");   // once, orders agg reads below
  {
    const int j = t >> 2, n0 = (t & 3) * 4;
    if (j < c) {
#pragma unroll
      for (int q = 0; q < 4; ++q) {
        u64 v = __hip_atomic_load(&agg[((u64)b * 128 + j) * 16 + n0 + q],
                                  __ATOMIC_RELAXED, __HIP_MEMORY_SCOPE_AGENT);
        sAX[j][n0 + q][0] = __uint_as_float((u32)v);
        sAX[j][n0 + q][1] = __uint_as_float((u32)(v >> 32));
      }
    } else {
#pragma unroll
      for (int q = 0; q < 4; ++q) { sAX[j][n0 + q][0] = 1.f; sAX[j][n0 + q][1] = 0.f; }
    }
  }
  __syncthreads();
  for (int st = 1; st < 128; st <<= 1) {
    const int cnt = (128 / (2 * st)) * 16;
    for (int idx = t; idx < cnt; idx += 512) {
      const int jj = (idx >> 4) * 2 * st, n = idx & 15;
      float A1 = sAX[jj][n][0], X1 = sAX[jj][n][1];
      float A2 = sAX[jj + st][n][0], X2 = sAX[jj + st][n][1];
      sAX[jj][n][0] = A2 * A1;          // apply [jj] then [jj+st]
      sAX[jj][n][1] = A2 * X1 + X2;
    }
    __syncthreads();
  }

  // ---- phase D: reconstruct h for the 16 rows ----
  if (t < 16) {
    float h = sAX[0][t][1];             // state entering this chunk (h0 = 0)
#pragma unroll
    for (int r = 0; r < 16; ++r) {
      h = aL[r][t] * h + xL[r][t];
      sh[r][t] = h;
    }
  }
  __syncthreads();

  // ---- phase E: y[16 rows] = h . C ----
  f4v c16[16];
#pragma unroll
  for (int nn = 0; nn < 16; ++nn)
    c16[nn] = *(const f4v*)&C[nn * DMODEL + t * 4];
#pragma unroll 2
  for (int r = 0; r < 16; ++r) {
    f4v o = {0.f, 0.f, 0.f, 0.f};
#pragma unroll
    for (int nn = 0; nn < 16; ++nn) o += sh[r][nn] * c16[nn];
    __builtin_nontemporal_store(o, (f4v*)&y[(row0 + r) * DMODEL + t * 4]);
  }
}

extern "C" void kernel_launch(void* const* d_in, const int* in_sizes, int n_in,
                              void* d_out, int out_size, void* d_ws, size_t ws_size,
                              hipStream_t stream) {
  const float* x    = (const float*)d_in[0];
  const float* Alog = (const float*)d_in[1];
  const float* Bm   = (const float*)d_in[2];
  const float* Cm   = (const float*)d_in[3];
  const float* dtw  = (const float*)d_in[4];
  const float* dtb  = (const float*)d_in[5];
  const float* dtpw = (const float*)d_in[6];
  float* y = (float*)d_out;

  char* w = (char*)d_ws;
  u16*   Wcb   = (u16*)w; w += (size_t)32 * DMODEL * 2;   // 128 KB
  float* bias2 = (float*)w; w += 256;
  u64*   agg   = (u64*)w; w += (size_t)512 * 16 * 8;      // 64 KB
  u32*   stat  = (u32*)w; w += (size_t)512 * 4;           // 2 KB

  build_wc<<<128, 256, 0, stream>>>(dtw, dtpw, dtb, Bm, Wcb, bias2, stat);
  mega<<<512, 512, 0, stream>>>(x, Wcb, bias2, Alog, Cm, agg, stat, y);
}

// Round 8
// 55.302 us; speedup vs baseline: 1.8869x; 1.7871x over previous
//
#include <hip/hip_runtime.h>
#include <hip/hip_bf16.h>

typedef unsigned short u16;
typedef unsigned int u32;
typedef short s8v __attribute__((ext_vector_type(8)));
typedef float f4v __attribute__((ext_vector_type(4)));

#define DMODEL 2048

__device__ __forceinline__ u16 f2bf(float f) {
  unsigned u = __float_as_uint(f);
  u += 0x7fffu + ((u >> 16) & 1u);
  return (u16)(u >> 16);
}

__device__ __forceinline__ u32 pkbf(float lo, float hi) {
  __hip_bfloat162 h = __float22bfloat162_rn(make_float2(lo, hi));
  return *reinterpret_cast<const u32*>(&h);
}

// ---------------- kernel 1: Wcb[32][2048] bf16 + bias2 ----------------
__global__ __launch_bounds__(256) void build_wc(const float* __restrict__ dtw,
                                                const float* __restrict__ dtpw,
                                                const float* __restrict__ dtb,
                                                const float* __restrict__ Bm,
                                                u16* __restrict__ Wcb,
                                                float* __restrict__ bias2) {
  __shared__ float spw[512 * 16];
  __shared__ float sdw[64][16];
  const int t = threadIdx.x;
  const int k0 = blockIdx.x * 16;
  for (int i = t; i < 2048; i += 256)
    *(float4*)&spw[i * 4] = *(const float4*)&dtpw[i * 4];
  const int kk = t >> 4, n = t & 15;
  const int srr = t >> 2, sc4 = (t & 3) * 4;
  float acc = 0.f;
  for (int rc = 0; rc < 8; ++rc) {
    __syncthreads();
    *(float4*)&sdw[srr][sc4] = *(const float4*)&dtw[(rc * 64 + srr) * DMODEL + k0 + sc4];
    __syncthreads();
#pragma unroll 8
    for (int rr = 0; rr < 64; ++rr)
      acc += sdw[rr][kk] * spw[(rc * 64 + rr) * 16 + n];
  }
  Wcb[n * DMODEL + k0 + kk] = f2bf(acc);
  Wcb[(16 + n) * DMODEL + k0 + kk] = f2bf(Bm[(k0 + kk) * 16 + n]);
  if (blockIdx.x == 0 && t < 16) {
    float s0 = 0.f, s1 = 0.f;
    for (int r = 0; r < 512; r += 2) {
      s0 += dtb[r] * spw[r * 16 + t];
      s1 += dtb[r + 1] * spw[(r + 1) * 16 + t];
    }
    bias2[t] = s0 + s1;
  }
}

// ---------------- kernel 2: GEMM  x -> (abar_t, xb_t, chunk summaries) ----------------
// 512 blocks x 8 waves; block = 16 x-rows (= one scan chunk); wave w owns K-chunk.
__global__ __launch_bounds__(512) void fused_main(const float* __restrict__ x,
                                                  const u16* __restrict__ Wcb,
                                                  const float* __restrict__ bias2,
                                                  const float* __restrict__ Alog,
                                                  float* __restrict__ abar_t,
                                                  float* __restrict__ xb_t,
                                                  float* __restrict__ As,
                                                  float* __restrict__ Xs) {
  __shared__ float red[8][8][64];   // 16 KB
  __shared__ float aL[16][17], xL[16][17];
  const int t = threadIdx.x, w = t >> 6, l = t & 63;
  const int lr = l & 15, lh = l >> 4;
  const int row0 = blockIdx.x * 16;
  const int k0 = w * 256;

  f4v acc0 = {0.f, 0.f, 0.f, 0.f}, acc1 = {0.f, 0.f, 0.f, 0.f};
  const float* xp  = x + (long)(row0 + lr) * DMODEL + k0 + lh * 8;
  const u16*   wp0 = Wcb + lr * DMODEL + k0 + lh * 8;
  const u16*   wp1 = Wcb + (16 + lr) * DMODEL + k0 + lh * 8;

#pragma unroll
  for (int ks = 0; ks < 8; ++ks) {
    f4v u0 = __builtin_nontemporal_load((const f4v*)(xp + ks * 32));
    f4v u1 = __builtin_nontemporal_load((const f4v*)(xp + ks * 32 + 4));
    union { u32 d[4]; s8v v; } pa;
    pa.d[0] = pkbf(u0[0], u0[1]); pa.d[1] = pkbf(u0[2], u0[3]);
    pa.d[2] = pkbf(u1[0], u1[1]); pa.d[3] = pkbf(u1[2], u1[3]);
    s8v b0 = *(const s8v*)(wp0 + ks * 32);
    s8v b1 = *(const s8v*)(wp1 + ks * 32);
    acc0 = __builtin_amdgcn_mfma_f32_16x16x32_bf16(pa.v, b0, acc0, 0, 0, 0);
    acc1 = __builtin_amdgcn_mfma_f32_16x16x32_bf16(pa.v, b1, acc1, 0, 0, 0);
  }
#pragma unroll
  for (int q = 0; q < 4; ++q) { red[q][w][l] = acc0[q]; red[4 + q][w][l] = acc1[q]; }
  __syncthreads();

  float s = 0.f;
#pragma unroll
  for (int ww = 0; ww < 8; ++ww) s += red[w][ww][l];

  const int n = lr;
  const int row = lh * 4 + (w & 3);
  const int b = row0 >> 11, srow = row0 & 2047;
  const long idx = ((long)b * 16 + n) * 2048 + srow + row;
  if (w < 4) {
    float d2 = s + bias2[n];
    float sig = 1.f / (1.f + __expf(-d2));
    float delta = 0.001f + 0.099f * sig;
    float av = __expf(delta * __expf(Alog[n]));
    abar_t[idx] = av;
    aL[row][n] = av;
  } else {
    xb_t[idx] = s;
    xL[row][n] = s;
  }
  __syncthreads();
  if (t < 16) {
    float A = 1.f, X = 0.f;
#pragma unroll
    for (int r = 0; r < 16; ++r) {
      float a = aL[r][t];
      X = a * X + xL[r][t];
      A *= a;
    }
    const int chunk = srow >> 4;
    As[((long)b * 16 + t) * 128 + chunk] = A;
    Xs[((long)b * 16 + t) * 128 + chunk] = X;
  }
}

// ---------------- kernel 3: redundant summary-scan + reconstruct + projection ----------------
// 512 blocks x 512 thr; block bid: b = bid>>7, chunk c = bid&127, rows [bid*16, +16).
// Each block re-scans its batch's 128 chunk summaries in LDS (no cross-block sync).
__global__ __launch_bounds__(512) void scan_proj(const float* __restrict__ abar_t,
                                                 const float* __restrict__ xb_t,
                                                 const float* __restrict__ As,
                                                 const float* __restrict__ Xs,
                                                 const float* __restrict__ C,
                                                 float* __restrict__ y) {
  __shared__ float sc[2][128][16][2];   // ping-pong scan buffer, 32 KB
  __shared__ float sa[16][16], sx[16][16], sh[16][16];
  const int t = threadIdx.x;
  const int bid = blockIdx.x, b = bid >> 7, c = bid & 127;
  const long row0 = (long)bid * 16;
  const int s0 = c * 16;

  // C columns for this thread (hoisted; held through scan phase)
  f4v c16[16];
#pragma unroll
  for (int nn = 0; nn < 16; ++nn)
    c16[nn] = *(const f4v*)&C[nn * DMODEL + t * 4];

  // load per-row (a,x) for this chunk's 16 rows
  if (t < 256) {
    const int n = t >> 4, r = t & 15;
    const long bn = (long)b * 16 + n;
    sa[r][n] = abar_t[bn * 2048 + s0 + r];
    sx[r][n] = xb_t[bn * 2048 + s0 + r];
  }
  // load all 128 chunk summaries for batch b (float4 over chunks)
  {
    const int n = t >> 5, j0 = (t & 31) * 4;
    const long bn = (long)b * 16 + n;
    float4 va = *(const float4*)&As[bn * 128 + j0];
    float4 vx = *(const float4*)&Xs[bn * 128 + j0];
    sc[0][j0 + 0][n][0] = va.x; sc[0][j0 + 0][n][1] = vx.x;
    sc[0][j0 + 1][n][0] = va.y; sc[0][j0 + 1][n][1] = vx.y;
    sc[0][j0 + 2][n][0] = va.z; sc[0][j0 + 2][n][1] = vx.z;
    sc[0][j0 + 3][n][0] = va.w; sc[0][j0 + 3][n][1] = vx.w;
  }
  __syncthreads();

  // Hillis-Steele inclusive scan over chunks (composition), all 16 n in parallel
  int src = 0;
  for (int d = 1; d < 128; d <<= 1) {
#pragma unroll
    for (int q = 0; q < 4; ++q) {
      const int idx = t + q * 512;          // 0..2047
      const int j = idx >> 4, n = idx & 15;
      float A = sc[src][j][n][0], X = sc[src][j][n][1];
      if (j >= d) {
        float Ap = sc[src][j - d][n][0], Xp = sc[src][j - d][n][1];
        X = A * Xp + X;                     // earlier window first
        A = A * Ap;
      }
      sc[src ^ 1][j][n][0] = A; sc[src ^ 1][j][n][1] = X;
    }
    __syncthreads();
    src ^= 1;
  }

  // reconstruct h for the 16 rows of this chunk
  if (t < 16) {
    float h = (c == 0) ? 0.f : sc[src][c - 1][t][1];   // state entering chunk c
#pragma unroll
    for (int r = 0; r < 16; ++r) {
      h = sa[r][t] * h + sx[r][t];
      sh[r][t] = h;
    }
  }
  __syncthreads();

  // projection: y[16 rows] = h . C
#pragma unroll 2
  for (int r = 0; r < 16; ++r) {
    f4v o = {0.f, 0.f, 0.f, 0.f};
#pragma unroll
    for (int nn = 0; nn < 16; ++nn) o += sh[r][nn] * c16[nn];
    __builtin_nontemporal_store(o, (f4v*)&y[(row0 + r) * DMODEL + t * 4]);
  }
}

extern "C" void kernel_launch(void* const* d_in, const int* in_sizes, int n_in,
                              void* d_out, int out_size, void* d_ws, size_t ws_size,
                              hipStream_t stream) {
  const float* x    = (const float*)d_in[0];
  const float* Alog = (const float*)d_in[1];
  const float* Bm   = (const float*)d_in[2];
  const float* Cm   = (const float*)d_in[3];
  const float* dtw  = (const float*)d_in[4];
  const float* dtb  = (const float*)d_in[5];
  const float* dtpw = (const float*)d_in[6];
  float* y = (float*)d_out;

  char* w = (char*)d_ws;
  u16*   Wcb   = (u16*)w; w += (size_t)32 * DMODEL * 2;   // 128 KB
  float* bias2 = (float*)w; w += 256;
  float* ab_t  = (float*)w; w += (size_t)64 * 2048 * 4;   // 512 KB
  float* xb_t  = (float*)w; w += (size_t)64 * 2048 * 4;   // 512 KB
  float* As    = (float*)w; w += (size_t)64 * 128 * 4;    // 32 KB
  float* Xs    = (float*)w; w += (size_t)64 * 128 * 4;    // 32 KB

  build_wc<<<128, 256, 0, stream>>>(dtw, dtpw, dtb, Bm, Wcb, bias2);
  fused_main<<<512, 512, 0, stream>>>(x, Wcb, bias2, Alog, ab_t, xb_t, As, Xs);
  scan_proj<<<512, 512, 0, stream>>>(ab_t, xb_t, As, Xs, Cm, y);
}

// Round 9
// 53.530 us; speedup vs baseline: 1.9493x; 1.0331x over previous
//
#include <hip/hip_runtime.h>
#include <hip/hip_bf16.h>

typedef unsigned short u16;
typedef unsigned int u32;
typedef short s8v __attribute__((ext_vector_type(8)));
typedef float f4v __attribute__((ext_vector_type(4)));

#define DMODEL 2048

__device__ __forceinline__ u16 f2bf(float f) {
  unsigned u = __float_as_uint(f);
  u += 0x7fffu + ((u >> 16) & 1u);
  return (u16)(u >> 16);
}

__device__ __forceinline__ u32 pkbf(float lo, float hi) {
  __hip_bfloat162 h = __float22bfloat162_rn(make_float2(lo, hi));
  return *reinterpret_cast<const u32*>(&h);
}

// ---------------- kernel 1: Wcb[32][2048] bf16 (k-contiguous rows) ----------------
__global__ __launch_bounds__(256) void build_wc(const float* __restrict__ dtw,
                                                const float* __restrict__ dtpw,
                                                const float* __restrict__ dtb,
                                                const float* __restrict__ Bm,
                                                u16* __restrict__ Wcb,
                                                float* __restrict__ bias2) {
  __shared__ float spw[512 * 16];
  __shared__ float sdw[64][16];
  const int t = threadIdx.x;
  const int k0 = blockIdx.x * 16;
  for (int i = t; i < 2048; i += 256)
    *(float4*)&spw[i * 4] = *(const float4*)&dtpw[i * 4];
  const int kk = t >> 4, n = t & 15;
  const int srr = t >> 2, sc4 = (t & 3) * 4;
  float acc = 0.f;
  for (int rc = 0; rc < 8; ++rc) {
    __syncthreads();
    *(float4*)&sdw[srr][sc4] = *(const float4*)&dtw[(rc * 64 + srr) * DMODEL + k0 + sc4];
    __syncthreads();
#pragma unroll 8
    for (int rr = 0; rr < 64; ++rr)
      acc += sdw[rr][kk] * spw[(rc * 64 + rr) * 16 + n];
  }
  Wcb[n * DMODEL + k0 + kk] = f2bf(acc);
  Wcb[(16 + n) * DMODEL + k0 + kk] = f2bf(Bm[(k0 + kk) * 16 + n]);
  if (blockIdx.x == 0 && t < 16) {
    float s0 = 0.f, s1 = 0.f;
    for (int r = 0; r < 512; r += 2) {
      s0 += dtb[r] * spw[r * 16 + t];
      s1 += dtb[r + 1] * spw[(r + 1) * 16 + t];
    }
    bias2[t] = s0 + s1;
  }
}

// ---------------- kernel 2: fused  x -> (abar_t, xb_t, chunk summaries) ----------------
// 512 blocks x 8 waves; block = 16 x-rows (= one scan chunk); wave w owns K-chunk.
__global__ __launch_bounds__(512) void fused_main(const float* __restrict__ x,
                                                  const u16* __restrict__ Wcb,
                                                  const float* __restrict__ bias2,
                                                  const float* __restrict__ Alog,
                                                  float* __restrict__ abar_t,
                                                  float* __restrict__ xb_t,
                                                  float* __restrict__ As,
                                                  float* __restrict__ Xs) {
  __shared__ float red[8][8][64];   // 16 KB
  __shared__ float aL[16][17], xL[16][17];
  const int t = threadIdx.x, w = t >> 6, l = t & 63;
  const int lr = l & 15, lh = l >> 4;
  const int row0 = blockIdx.x * 16;
  const int k0 = w * 256;

  f4v acc0 = {0.f, 0.f, 0.f, 0.f}, acc1 = {0.f, 0.f, 0.f, 0.f};
  const float* xp  = x + (long)(row0 + lr) * DMODEL + k0 + lh * 8;
  const u16*   wp0 = Wcb + lr * DMODEL + k0 + lh * 8;
  const u16*   wp1 = Wcb + (16 + lr) * DMODEL + k0 + lh * 8;

#pragma unroll
  for (int ks = 0; ks < 8; ++ks) {
    f4v u0 = __builtin_nontemporal_load((const f4v*)(xp + ks * 32));
    f4v u1 = __builtin_nontemporal_load((const f4v*)(xp + ks * 32 + 4));
    union { u32 d[4]; s8v v; } pa;
    pa.d[0] = pkbf(u0[0], u0[1]); pa.d[1] = pkbf(u0[2], u0[3]);
    pa.d[2] = pkbf(u1[0], u1[1]); pa.d[3] = pkbf(u1[2], u1[3]);
    s8v b0 = *(const s8v*)(wp0 + ks * 32);
    s8v b1 = *(const s8v*)(wp1 + ks * 32);
    acc0 = __builtin_amdgcn_mfma_f32_16x16x32_bf16(pa.v, b0, acc0, 0, 0, 0);
    acc1 = __builtin_amdgcn_mfma_f32_16x16x32_bf16(pa.v, b1, acc1, 0, 0, 0);
  }
#pragma unroll
  for (int q = 0; q < 4; ++q) { red[q][w][l] = acc0[q]; red[4 + q][w][l] = acc1[q]; }
  __syncthreads();

  float s = 0.f;
#pragma unroll
  for (int ww = 0; ww < 8; ++ww) s += red[w][ww][l];

  const int n = lr;
  const int row = lh * 4 + (w & 3);
  const int b = row0 >> 11, srow = row0 & 2047;
  const long idx = ((long)b * 16 + n) * 2048 + srow + row;
  if (w < 4) {
    float d2 = s + bias2[n];
    float sig = 1.f / (1.f + __expf(-d2));
    float delta = 0.001f + 0.099f * sig;
    float av = __expf(delta * __expf(Alog[n]));
    abar_t[idx] = av;
    aL[row][n] = av;
  } else {
    xb_t[idx] = s;
    xL[row][n] = s;
  }
  __syncthreads();
  if (t < 16) {
    float A = 1.f, X = 0.f;
#pragma unroll
    for (int r = 0; r < 16; ++r) {
      float a = aL[r][t];
      X = a * X + xL[r][t];
      A *= a;
    }
    const int chunk = srow >> 4;
    As[((long)b * 16 + t) * 128 + chunk] = A;
    Xs[((long)b * 16 + t) * 128 + chunk] = X;
  }
}

// ---------------- kernel 3: scan the 128 chunk summaries per (b,n) -> H0 ----------------
// 16 blocks x 4 waves; wave = one (b,n); lane holds chunks 2l, 2l+1.
__global__ __launch_bounds__(256) void scan_sum(const float* __restrict__ As,
                                                const float* __restrict__ Xs,
                                                float* __restrict__ H0) {
  const int t = threadIdx.x, w = t >> 6, lane = t & 63;
  const long bn = blockIdx.x * 4 + w;
  float a0 = As[bn * 128 + 2 * lane], x0 = Xs[bn * 128 + 2 * lane];
  float a1 = As[bn * 128 + 2 * lane + 1], x1 = Xs[bn * 128 + 2 * lane + 1];
  float Ac = a1 * a0, Xc = a1 * x0 + x1;   // compose chunk 2l then 2l+1
#pragma unroll
  for (int d = 1; d < 64; d <<= 1) {
    float pa = __shfl_up(Ac, d);
    float px = __shfl_up(Xc, d);
    if (lane >= d) { Xc = Ac * px + Xc; Ac = Ac * pa; }
  }
  float Xprev = __shfl_up(Xc, 1);
  if (lane == 0) Xprev = 0.f;
  H0[bn * 128 + 2 * lane]     = Xprev;            // state entering chunk 2l
  H0[bn * 128 + 2 * lane + 1] = a0 * Xprev + x0;  // state entering chunk 2l+1
}

// ---------------- kernel 4: reconstruct h + y = hs @ C ----------------
__global__ __launch_bounds__(512) void proj(const float* __restrict__ abar_t,
                                            const float* __restrict__ xb_t,
                                            const float* __restrict__ H0,
                                            const float* __restrict__ C,
                                            float* __restrict__ y) {
  __shared__ float sh[32 * 16];
  __shared__ float sa[16][32], sx[16][32];
  const int t = threadIdx.x;
  const int bB = blockIdx.x >> 6;
  const int s0 = (blockIdx.x & 63) * 32;
  const long row0 = (long)blockIdx.x * 32;
  {
    const int n = t >> 5, ss = t & 31;
    const long bn = (long)bB * 16 + n;
    sa[n][ss] = abar_t[bn * 2048 + s0 + ss];
    sx[n][ss] = xb_t[bn * 2048 + s0 + ss];
  }
  float4 c[16];
#pragma unroll
  for (int nn = 0; nn < 16; ++nn) c[nn] = *(const float4*)&C[nn * DMODEL + t * 4];
  __syncthreads();
  if (t < 32) {
    const int n = t & 15, cc = t >> 4;
    const long bn = (long)bB * 16 + n;
    float h = H0[bn * 128 + (s0 >> 4) + cc];
#pragma unroll
    for (int i = 0; i < 16; ++i) {
      int r = cc * 16 + i;
      h = sa[n][r] * h + sx[n][r];
      sh[r * 16 + n] = h;
    }
  }
  __syncthreads();
#pragma unroll 4
  for (int r = 0; r < 32; ++r) {
    const float* h = &sh[r * 16];
    f4v o = {0.f, 0.f, 0.f, 0.f};
#pragma unroll
    for (int nn = 0; nn < 16; ++nn) {
      float hv = h[nn];
      o[0] += hv * c[nn].x; o[1] += hv * c[nn].y;
      o[2] += hv * c[nn].z; o[3] += hv * c[nn].w;
    }
    __builtin_nontemporal_store(o, (f4v*)&y[(row0 + r) * DMODEL + t * 4]);
  }
}

extern "C" void kernel_launch(void* const* d_in, const int* in_sizes, int n_in,
                              void* d_out, int out_size, void* d_ws, size_t ws_size,
                              hipStream_t stream) {
  const float* x    = (const float*)d_in[0];
  const float* Alog = (const float*)d_in[1];
  const float* Bm   = (const float*)d_in[2];
  const float* Cm   = (const float*)d_in[3];
  const float* dtw  = (const float*)d_in[4];
  const float* dtb  = (const float*)d_in[5];
  const float* dtpw = (const float*)d_in[6];
  float* y = (float*)d_out;

  char* w = (char*)d_ws;
  u16*   Wcb   = (u16*)w; w += (size_t)32 * DMODEL * 2;   // 128 KB
  float* bias2 = (float*)w; w += 256;
  float* ab_t  = (float*)w; w += (size_t)64 * 2048 * 4;   // 512 KB
  float* xb_t  = (float*)w; w += (size_t)64 * 2048 * 4;   // 512 KB
  float* As    = (float*)w; w += (size_t)64 * 128 * 4;    // 32 KB
  float* Xs    = (float*)w; w += (size_t)64 * 128 * 4;    // 32 KB
  float* H0    = (float*)w; w += (size_t)64 * 128 * 4;    // 32 KB

  build_wc<<<128, 256, 0, stream>>>(dtw, dtpw, dtb, Bm, Wcb, bias2);
  fused_main<<<512, 512, 0, stream>>>(x, Wcb, bias2, Alog, ab_t, xb_t, As, Xs);
  scan_sum<<<16, 256, 0, stream>>>(As, Xs, H0);
  proj<<<256, 512, 0, stream>>>(ab_t, xb_t, H0, Cm, y);
}